// Round 1
// baseline (311.188 us; speedup 1.0000x reference)
//
#include <hip/hip_runtime.h>

// Problem constants (from reference)
#define NN      8192
#define N_IN    64
#define N_OUT   32
#define E_REC   65536
#define DD      4
#define ROW0    (NN - N_OUT)      // 8160: first output row

// Workspace layout (floats):
//   [0, 256)            : matvec partials, slot r*8 + c  (r in [0,32), c in [0,8))
//   [256, 256 + 64*32)  : edge partials,   slot 256 + eb*32 + r
#define MV_BLOCKS   256
#define EDGE_BLOCKS 64

__global__ __launch_bounds__(256) void partials_kernel(
    const float* __restrict__ obs,
    const float* __restrict__ W,
    const float* __restrict__ current,
    const float* __restrict__ history,
    const float* __restrict__ rec_w,
    const int*   __restrict__ rec_src,
    const int*   __restrict__ rec_dst,
    const int*   __restrict__ rec_delay,
    float*       __restrict__ ws)
{
    const int b = blockIdx.x;
    const int t = threadIdx.x;

    if (b < MV_BLOCKS) {
        // ---- dense matvec partial: row ROW0+r, columns [c*1024, c*1024+1024) ----
        const int r   = b >> 3;   // 0..31
        const int c   = b & 7;    // 0..7
        const int col = c * 1024 + t * 4;

        const float4 w4 = *(const float4*)(W + (size_t)(ROW0 + r) * NN + col);
        // h_prev[j] = obs[j] for j < 64, else current[j].  64 % 4 == 0, so each
        // float4 group is entirely one or the other.
        float4 h4;
        if (col < N_IN) h4 = *(const float4*)(obs + col);
        else            h4 = *(const float4*)(current + col);

        float v = w4.x * h4.x + w4.y * h4.y + w4.z * h4.z + w4.w * h4.w;

        // wave64 shuffle reduction
        #pragma unroll
        for (int off = 32; off > 0; off >>= 1)
            v += __shfl_down(v, off, 64);

        __shared__ float smem[4];
        if ((t & 63) == 0) smem[t >> 6] = v;
        __syncthreads();
        if (t == 0)
            ws[r * 8 + c] = smem[0] + smem[1] + smem[2] + smem[3];
    } else {
        // ---- recurrent edges: 1024 edges per block, keep only dst >= ROW0 ----
        const int eb = b - MV_BLOCKS;
        __shared__ float acc[N_OUT];
        if (t < N_OUT) acc[t] = 0.0f;
        __syncthreads();

        const int base = eb * 1024;
        #pragma unroll
        for (int k = 0; k < 4; ++k) {
            const int e   = base + k * 256 + t;
            const int dst = rec_dst[e];
            if (dst >= ROW0) {
                const float val = rec_w[e] * history[rec_src[e] * DD + rec_delay[e]];
                atomicAdd(&acc[dst - ROW0], val);   // LDS atomic, ~1 hit/block
            }
        }
        __syncthreads();
        if (t < N_OUT)
            ws[MV_BLOCKS + eb * N_OUT + t] = acc[t];
    }
}

__global__ __launch_bounds__(64) void finalize_kernel(
    const float* __restrict__ bias,
    const float* __restrict__ ws,
    float*       __restrict__ out)
{
    const int r = threadIdx.x;
    if (r < N_OUT) {
        float s = bias[ROW0 + r];
        #pragma unroll
        for (int c = 0; c < 8; ++c)
            s += ws[r * 8 + c];
        #pragma unroll 8
        for (int eb = 0; eb < EDGE_BLOCKS; ++eb)
            s += ws[MV_BLOCKS + eb * N_OUT + r];
        out[r] = tanhf(s);
    }
}

extern "C" void kernel_launch(void* const* d_in, const int* in_sizes, int n_in,
                              void* d_out, int out_size, void* d_ws, size_t ws_size,
                              hipStream_t stream) {
    const float* obs       = (const float*)d_in[0];
    const float* W         = (const float*)d_in[1];
    const float* bias      = (const float*)d_in[2];
    const float* current   = (const float*)d_in[3];
    const float* history   = (const float*)d_in[4];
    const float* rec_w     = (const float*)d_in[5];
    const int*   rec_src   = (const int*)d_in[6];
    const int*   rec_dst   = (const int*)d_in[7];
    const int*   rec_delay = (const int*)d_in[8];
    float* out = (float*)d_out;
    float* ws  = (float*)d_ws;

    partials_kernel<<<MV_BLOCKS + EDGE_BLOCKS, 256, 0, stream>>>(
        obs, W, current, history, rec_w, rec_src, rec_dst, rec_delay, ws);
    finalize_kernel<<<1, 64, 0, stream>>>(bias, ws, out);
}